// Round 8
// baseline (2486.043 us; speedup 1.0000x reference)
//
#include <hip/hip_runtime.h>
#include <hip/hip_bf16.h>
#include <math.h>

#define MTOK 16384      // B*L tokens
#define DM   768
#define DI   1536
#define DS   16
#define RNK  48
#define LSEQ 2048
#define NBATCH 8
#define EPSV 1e-5f
#define CHK  16         // time chunks for the scan
#define CLEN (LSEQ / CHK)
#define BM 128
#define BN 128
#define BK 32
#define KSPLIT 8        // split-K factor for the x_proj GEMM
#define EPS_STRIDE 72   // epilogue LDS row stride (shorts)

typedef __hip_bfloat16 bf16;
typedef __attribute__((ext_vector_type(8))) short short8;
typedef __attribute__((ext_vector_type(4))) float floatx4;

__device__ __forceinline__ float b2f(bf16 v){ return __bfloat162float(v); }
__device__ __forceinline__ bf16  f2b(float v){ return __float2bfloat16(v); }
__device__ __forceinline__ float u2f(unsigned short u){
    union { unsigned int i; float f; } v; v.i = ((unsigned int)u) << 16; return v.f;
}
__device__ __forceinline__ float silu_f(float x){
    return x * __builtin_amdgcn_rcpf(1.f + __expf(-x));
}
__device__ __forceinline__ void gload_lds16(const void* g, void* l) {
    __builtin_amdgcn_global_load_lds(
        (const __attribute__((address_space(1))) void*)g,
        (__attribute__((address_space(3))) void*)l, 16, 0, 0);
}

// ---------------- fp32 -> bf16 convert ----------------
__global__ __launch_bounds__(256) void cvt_kernel(
    const float* __restrict__ x, bf16* __restrict__ h, int n)
{
    int i = blockIdx.x * 256 + threadIdx.x;
    if (i < n) h[i] = f2b(x[i]);
}

// ---------------- fp32 [rows,sc] -> bf16 [rows,dc] zero-padded ----------------
__global__ __launch_bounds__(256) void cvt_pad_kernel(
    const float* __restrict__ x, bf16* __restrict__ o, int sc, int dc, int n)
{
    int i = blockIdx.x * 256 + threadIdx.x;
    if (i >= n) return;
    int col = i % dc;
    int row = i / dc;
    o[i] = (col < sc) ? f2b(x[(size_t)row * sc + col]) : f2b(0.f);
}

// ---------------- RMSNorm over 768 (3 elems/thread) ----------------
__global__ __launch_bounds__(256) void rmsnorm_kernel(
    const bf16* __restrict__ in, const float* __restrict__ w,
    bf16* __restrict__ out, float* __restrict__ rs_out)
{
    int row = blockIdx.x;
    const bf16* r = in + (size_t)row * DM;
    float v0 = b2f(r[threadIdx.x]);
    float v1 = b2f(r[threadIdx.x + 256]);
    float v2 = b2f(r[threadIdx.x + 512]);
    float s = v0*v0 + v1*v1 + v2*v2;
    for (int o = 32; o > 0; o >>= 1) s += __shfl_down(s, o, 64);
    __shared__ float red[4];
    if ((threadIdx.x & 63) == 0) red[threadIdx.x >> 6] = s;
    __syncthreads();
    float rs = rsqrtf((red[0]+red[1]+red[2]+red[3]) * (1.f/DM) + EPSV);
    if (rs_out && threadIdx.x == 0) rs_out[row] = rs;
    if (out) {
        out[(size_t)row*DM + threadIdx.x]       = f2b(v0 * rs * w[threadIdx.x]);
        out[(size_t)row*DM + threadIdx.x + 256] = f2b(v1 * rs * w[threadIdx.x + 256]);
        out[(size_t)row*DM + threadIdx.x + 512] = f2b(v2 * rs * w[threadIdx.x + 512]);
    }
}

// ---------------- bf16 MFMA GEMM: C[M,N] (op)= A[M,K] @ W[N,K]^T ----------------
// MODE 0: C = acc ; MODE 1: C = softplus(acc + ep_bias[n]) ; MODE 2: C += acc ;
// MODE 3: C = C * silu(acc) ; MODE 4: atomicAdd fp32 partials (split-K)
// CONVA=1: A-tile = silu(causal dwconv4(A)) computed on the fly
template<int MODE, int CONVA>
__global__ __launch_bounds__(256) void mgemm(
    const short* __restrict__ A, int lda,
    const short* __restrict__ W, int ldw,
    bf16* __restrict__ C, int ldc,
    int M, int N, int K,
    const float* __restrict__ cw, const float* __restrict__ cb,
    const float* __restrict__ ep_bias,
    int ksteps_per_split)
{
    __shared__ __attribute__((aligned(16))) short As[BM*BK];
    __shared__ __attribute__((aligned(16))) short Bs[BN*BK];
    const int bm = blockIdx.y * BM;
    const int bn = blockIdx.x * BN;
    const int tid = threadIdx.x;
    const int wave = tid >> 6;
    const int lane = tid & 63;
    const int wm = (wave & 1) * 64;
    const int wn = (wave >> 1) * 64;
    const int r15 = lane & 15;
    const int quad = lane >> 4;

    int kbeg = 0, kend = K;
    if (MODE == 4) {
        kbeg = blockIdx.z * ksteps_per_split * BK;
        kend = kbeg + ksteps_per_split * BK;
        if (kend > K) kend = K;
    }

    const int srow = wave*32 + (lane >> 2);
    const int swz = (lane & 3) ^ ((lane >> 2) & 3);
    int wr0 = bn + srow;      if (wr0 >= N) wr0 = N - 1;
    int wr1 = bn + srow + 16; if (wr1 >= N) wr1 = N - 1;

    floatx4 acc[4][4];
    const floatx4 zero = {0.f, 0.f, 0.f, 0.f};
    #pragma unroll
    for (int i = 0; i < 4; i++)
        #pragma unroll
        for (int j = 0; j < 4; j++) acc[i][j] = zero;

    const int kk = tid & 31;
    const int tg = tid >> 5;
    const int sA = CONVA ? quad : (quad ^ (r15 & 3));
    const int sB = quad ^ (r15 & 3);

    for (int k0 = kbeg; k0 < kend; k0 += BK) {
        if (CONVA) {
            int e = k0 + kk;
            float c0 = cw[e*4+0], c1 = cw[e*4+1], c2 = cw[e*4+2], c3 = cw[e*4+3];
            float cbe = cb[e];
            int g0 = bm + tg*16;
            const unsigned short* xp = (const unsigned short*)A + (size_t)g0 * lda + e;
            float p0 = 0.f, p1 = 0.f, p2 = 0.f;
            if ((g0 & (LSEQ-1)) != 0) {
                p0 = u2f(xp[-(ptrdiff_t)3*lda]);
                p1 = u2f(xp[-(ptrdiff_t)2*lda]);
                p2 = u2f(xp[-(ptrdiff_t)1*lda]);
            }
            #pragma unroll
            for (int i = 0; i < 16; i++) {
                float xt = u2f(xp[(size_t)i * lda]);
                float xv = silu_f(cbe + c0*p0 + c1*p1 + c2*p2 + c3*xt);
                p0 = p1; p1 = p2; p2 = xt;
                bf16 t = f2b(xv);
                As[(tg*16 + i)*BK + kk] = *(short*)&t;
            }
        } else {
            gload_lds16(A + (size_t)(bm + srow)      * lda + k0 + swz*8, &As[(wave*32)*BK]);
            gload_lds16(A + (size_t)(bm + srow + 16) * lda + k0 + swz*8, &As[(wave*32 + 16)*BK]);
        }
        gload_lds16(W + (size_t)wr0 * ldw + k0 + swz*8, &Bs[(wave*32)*BK]);
        gload_lds16(W + (size_t)wr1 * ldw + k0 + swz*8, &Bs[(wave*32 + 16)*BK]);
        __syncthreads();

        short8 af[4], bfr[4];
        #pragma unroll
        for (int i = 0; i < 4; i++) af[i]  = *(const short8*)&As[(wm + i*16 + r15)*BK + sA*8];
        #pragma unroll
        for (int i = 0; i < 4; i++) bfr[i] = *(const short8*)&Bs[(wn + i*16 + r15)*BK + sB*8];
        #pragma unroll
        for (int mt = 0; mt < 4; mt++)
            #pragma unroll
            for (int nt = 0; nt < 4; nt++)
                acc[mt][nt] = __builtin_amdgcn_mfma_f32_16x16x32_bf16(
                    af[mt], bfr[nt], acc[mt][nt], 0, 0, 0);
        __syncthreads();
    }

    if (MODE == 4) {
        float* Cf = (float*)C;
        #pragma unroll
        for (int nt = 0; nt < 4; nt++) {
            int n = bn + wn + nt*16 + r15;
            if (n >= N) continue;
            #pragma unroll
            for (int mt = 0; mt < 4; mt++)
                #pragma unroll
                for (int reg = 0; reg < 4; reg++) {
                    int m = bm + wm + mt*16 + quad*4 + reg;
                    atomicAdd(&Cf[(size_t)m * ldc + n], acc[mt][nt][reg]);
                }
        }
        return;
    }

    // ---- wide-store epilogue via per-wave LDS bounce ----
    short* ep = ((wave & 2) ? Bs : As) + (wave & 1) * 1152;
    const int lr = lane >> 2;
    const int lc = lane & 3;
    #pragma unroll
    for (int mt = 0; mt < 4; mt++) {
        #pragma unroll
        for (int nt = 0; nt < 4; nt++) {
            float bias = 0.f;
            if (MODE == 1) {
                int n = bn + wn + nt*16 + r15;
                bias = ep_bias[n < N ? n : N-1];
            }
            #pragma unroll
            for (int reg = 0; reg < 4; reg++) {
                float v = acc[mt][nt][reg];
                if (MODE == 1) {
                    v += bias;
                    v = (v > 20.f) ? v : __logf(1.f + __expf(v));
                }
                bf16 t = f2b(v);
                ep[(quad*4 + reg)*EPS_STRIDE + nt*16 + r15] = *(short*)&t;
            }
        }
        short8 v0 = *(const short8*)&ep[lr*EPS_STRIDE + lc*16];
        short8 v1 = *(const short8*)&ep[lr*EPS_STRIDE + lc*16 + 8];
        int gm = bm + wm + mt*16 + lr;
        int gn = bn + wn + lc*16;
        if (gn < N) {
            bf16* cp = C + (size_t)gm * ldc + gn;
            if (MODE == 0 || MODE == 1) {
                *(short8*)cp       = v0;
                *(short8*)(cp + 8) = v1;
            } else {
                short8 c0 = *(const short8*)cp;
                short8 c1 = *(const short8*)(cp + 8);
                short8 o0, o1;
                #pragma unroll
                for (int j = 0; j < 8; j++) {
                    float cv0 = u2f((unsigned short)c0[j]);
                    float av0 = u2f((unsigned short)v0[j]);
                    float cv1 = u2f((unsigned short)c1[j]);
                    float av1 = u2f((unsigned short)v1[j]);
                    float r0 = (MODE == 2) ? (cv0 + av0) : (cv0 * silu_f(av0));
                    float r1 = (MODE == 2) ? (cv1 + av1) : (cv1 * silu_f(av1));
                    bf16 t0 = f2b(r0), t1 = f2b(r1);
                    o0[j] = *(short*)&t0;
                    o1[j] = *(short*)&t1;
                }
                *(short8*)cp       = o0;
                *(short8*)(cp + 8) = o1;
            }
        }
    }
}

// ---------------- FUSED chunked scan: delta precomputed, z-gate in pass 2 ----
// xz [M,3072]: xin cols 0..1535 (y overwrites), z cols 1536..3071
template<int PASS>
__global__ __launch_bounds__(256) void scan_fused_kernel(
    bf16* __restrict__ xz,
    const bf16* __restrict__ delta,     // [M,1536] softplus'd
    const bf16* __restrict__ dbc,       // [M,128]: B at 48..63, C at 64..79
    const float* __restrict__ A_log, const float* __restrict__ Dp,
    const float* __restrict__ cw, const float* __restrict__ cb,
    float* __restrict__ hst, float* __restrict__ Ssum,
    unsigned short* __restrict__ bound)
{
    int e = (blockIdx.x % (DI/256)) * 256 + threadIdx.x;
    int b = (blockIdx.x / (DI/256)) & (NBATCH - 1);
    int c = blockIdx.x / ((DI/256) * NBATCH);
    int t0 = c * CLEN;

    float a[DS];
    #pragma unroll
    for (int n = 0; n < DS; n++) a[n] = -__expf(A_log[e*DS + n]);
    float c0 = cw[e*4+0], c1 = cw[e*4+1], c2 = cw[e*4+2], c3 = cw[e*4+3];
    float cbe = cb[e], dpe = Dp[e];

    size_t sidx = ((size_t)(b*DI) + e) * CHK + c;
    float hh[DS];
    if (PASS == 1) {
        #pragma unroll
        for (int n = 0; n < DS; n++) hh[n] = 0.f;
    } else {
        #pragma unroll
        for (int n = 0; n < DS; n++) hh[n] = hst[sidx*DS + n];
    }

    unsigned short* xrow = (unsigned short*)xz + ((size_t)(b*LSEQ) + t0) * 3072 + e;
    const unsigned short* drow = (const unsigned short*)delta + ((size_t)(b*LSEQ) + t0) * DI + e;
    const unsigned short* brow = (const unsigned short*)dbc + ((size_t)(b*LSEQ) + t0) * 128;

    unsigned short r0, r1, r2;
    if (PASS == 1) {
        if (c == 0) { r0 = 0; r1 = 0; r2 = 0; }
        else {
            r0 = xrow[-(ptrdiff_t)3*3072];
            r1 = xrow[-(ptrdiff_t)2*3072];
            r2 = xrow[-(ptrdiff_t)1*3072];
        }
        bound[sidx*4+0] = r0; bound[sidx*4+1] = r1; bound[sidx*4+2] = r2;
    } else {
        r0 = bound[sidx*4+0]; r1 = bound[sidx*4+1]; r2 = bound[sidx*4+2];
    }
    float p0 = u2f(r0), p1 = u2f(r1), p2 = u2f(r2);

    float S = 0.f;
    for (int t = 0; t < CLEN; t++) {
        float xt = u2f(xrow[(size_t)t * 3072]);
        float xv = silu_f(cbe + c0*p0 + c1*p1 + c2*p2 + c3*xt);
        p0 = p1; p1 = p2; p2 = xt;

        float d = u2f(drow[(size_t)t * DI]);

        uint4 qb[2];
        qb[0] = *(const uint4*)(brow + (size_t)t*128 + 48);
        qb[1] = *(const uint4*)(brow + (size_t)t*128 + 56);
        const unsigned short* Bv = (const unsigned short*)qb;

        float dx = d * xv;
        #pragma unroll
        for (int n = 0; n < DS; n++)
            hh[n] = __expf(d * a[n]) * hh[n] + dx * u2f(Bv[n]);

        if (PASS == 1) {
            S += d;
        } else {
            uint4 qc[2];
            qc[0] = *(const uint4*)(brow + (size_t)t*128 + 64);
            qc[1] = *(const uint4*)(brow + (size_t)t*128 + 72);
            const unsigned short* Cv = (const unsigned short*)qc;
            float y = xv * dpe;
            #pragma unroll
            for (int n = 0; n < DS; n++) y += hh[n] * u2f(Cv[n]);
            float zv = u2f(xrow[(size_t)t * 3072 + DI]);
            y *= silu_f(zv);
            bf16 yb = f2b(y);
            xrow[(size_t)t * 3072] = *(unsigned short*)&yb;
        }
    }
    if (PASS == 1) {
        #pragma unroll
        for (int n = 0; n < DS; n++) hst[sidx*DS + n] = hh[n];
        Ssum[sidx] = S;
    }
}

// ---------------- FALLBACK chunked scan (R7 verbatim) ----------------
template<int PASS>
__global__ __launch_bounds__(256) void scan_pass_kernel(
    bf16* __restrict__ xy, const bf16* __restrict__ dbc,
    const float* __restrict__ A_log, const float* __restrict__ Dp,
    const float* __restrict__ dtw, const float* __restrict__ dtb,
    const float* __restrict__ cw, const float* __restrict__ cb,
    float* __restrict__ hst, float* __restrict__ Ssum,
    unsigned short* __restrict__ bound)
{
    int e = (blockIdx.x % (DI/256)) * 256 + threadIdx.x;
    int b = (blockIdx.x / (DI/256)) & (NBATCH - 1);
    int c = blockIdx.x / ((DI/256) * NBATCH);
    int t0 = c * CLEN;

    float w[RNK];
    #pragma unroll
    for (int r = 0; r < RNK; r++) w[r] = dtw[e*RNK + r];
    float a[DS];
    #pragma unroll
    for (int n = 0; n < DS; n++) a[n] = -__expf(A_log[e*DS + n]);
    float c0 = cw[e*4+0], c1 = cw[e*4+1], c2 = cw[e*4+2], c3 = cw[e*4+3];
    float cbe = cb[e], dtbe = dtb[e], dpe = Dp[e];

    size_t sidx = ((size_t)(b*DI) + e) * CHK + c;
    float hh[DS];
    if (PASS == 1) {
        #pragma unroll
        for (int n = 0; n < DS; n++) hh[n] = 0.f;
    } else {
        #pragma unroll
        for (int n = 0; n < DS; n++) hh[n] = hst[sidx*DS + n];
    }

    unsigned short* xrow = (unsigned short*)(xy + ((size_t)(b*LSEQ) + t0) * DI + e);
    const unsigned short* drow = (const unsigned short*)(dbc + ((size_t)(b*LSEQ) + t0) * 80);

    unsigned short r0, r1, r2;
    if (PASS == 1) {
        if (c == 0) { r0 = 0; r1 = 0; r2 = 0; }
        else {
            r0 = xrow[-(ptrdiff_t)3*DI];
            r1 = xrow[-(ptrdiff_t)2*DI];
            r2 = xrow[-(ptrdiff_t)1*DI];
        }
        bound[sidx*4+0] = r0; bound[sidx*4+1] = r1; bound[sidx*4+2] = r2;
    } else {
        r0 = bound[sidx*4+0]; r1 = bound[sidx*4+1]; r2 = bound[sidx*4+2];
    }
    float p0 = u2f(r0), p1 = u2f(r1), p2 = u2f(r2);

    float S = 0.f;
    for (int t = 0; t < CLEN; t++) {
        float xt = u2f(xrow[(size_t)t * DI]);
        float xv = silu_f(cbe + c0*p0 + c1*p1 + c2*p2 + c3*xt);
        p0 = p1; p1 = p2; p2 = xt;

        uint4 q[5];
        const uint4* d4 = (const uint4*)(drow + (size_t)t * 80);
        #pragma unroll
        for (int i = 0; i < 5; i++) q[i] = d4[i];
        uint4 q2[5];
        #pragma unroll
        for (int i = 0; i < 5; i++) q2[i] = d4[5 + i];
        const unsigned short* ds = (const unsigned short*)q;
        const unsigned short* ds2 = (const unsigned short*)q2;

        float acc = dtbe;
        #pragma unroll
        for (int r = 0; r < RNK; r++) acc += w[r] * u2f(ds[r]);
        float d = (acc > 20.f) ? acc : __logf(1.f + __expf(acc));
        float dx = d * xv;
        #pragma unroll
        for (int n = 0; n < DS; n++)
            hh[n] = __expf(d * a[n]) * hh[n] + dx * u2f(ds[RNK + n]);

        if (PASS == 1) {
            S += d;
        } else {
            float y = xv * dpe;
            #pragma unroll
            for (int n = 0; n < DS; n++) y += hh[n] * u2f(ds2[n]);
            bf16 yb = f2b(y);
            xrow[(size_t)t * DI] = *(unsigned short*)&yb;
        }
    }
    if (PASS == 1) {
        #pragma unroll
        for (int n = 0; n < DS; n++) hst[sidx*DS + n] = hh[n];
        Ssum[sidx] = S;
    }
}

// ---------------- combine chunk states ----------------
__global__ __launch_bounds__(256) void scan_combine_kernel(
    float* __restrict__ hst, const float* __restrict__ Ssum,
    const float* __restrict__ A_log)
{
    int tid = blockIdx.x * 256 + threadIdx.x;
    int n = tid & 15;
    int bee = tid >> 4;
    int e = bee % DI;
    float a = -__expf(A_log[e*DS + n]);
    float run = 0.f;
    for (int c = 0; c < CHK; c++) {
        size_t idx = ((size_t)bee * CHK + c) * DS + n;
        float tmp = hst[idx];
        hst[idx] = run;
        run = tmp + __expf(a * Ssum[(size_t)bee*CHK + c]) * run;
    }
}

// ---------------- pooled / head ----------------
__global__ __launch_bounds__(128) void pool_kernel(
    const bf16* __restrict__ h, const float* __restrict__ rs,
    const float* __restrict__ wf, float* __restrict__ pooled)
{
    int b = blockIdx.x, dc = blockIdx.y, tc = blockIdx.z;
    int d = dc * 128 + threadIdx.x;
    float s = 0.f;
    int t0 = tc * 128;
    for (int t = t0; t < t0 + 128; t++) {
        int row = b * LSEQ + t;
        s += b2f(h[(size_t)row * DM + d]) * rs[row];
    }
    atomicAdd(&pooled[b * DM + d], s * wf[d] * (1.f / LSEQ));
}

__global__ __launch_bounds__(128) void head_kernel(
    const float* __restrict__ pooled, const float* __restrict__ cls_w,
    const float* __restrict__ cls_b, const int* __restrict__ labels,
    float* __restrict__ out)
{
    __shared__ float lg[80];
    int tid = threadIdx.x;
    if (tid < 80) {
        int b = tid / 10, c = tid % 10;
        float s = cls_b[c];
        for (int d = 0; d < DM; d++) s += pooled[b * DM + d] * cls_w[c * DM + d];
        lg[tid] = s;
    }
    __syncthreads();
    if (tid == 0) {
        float loss = 0.f;
        for (int b = 0; b < NBATCH; b++) {
            float mx = -1e30f;
            for (int c = 0; c < 10; c++) mx = fmaxf(mx, lg[b*10+c]);
            float se = 0.f;
            for (int c = 0; c < 10; c++) se += expf(lg[b*10+c] - mx);
            float lse = mx + logf(se);
            loss -= (lg[b*10 + labels[b]] - lse);
            for (int c = 0; c < 10; c++) out[b*10+c] = lg[b*10+c];
        }
        out[80] = loss / NBATCH;
    }
}

extern "C" void kernel_launch(void* const* d_in, const int* in_sizes, int n_in,
                              void* d_out, int out_size, void* d_ws, size_t ws_size,
                              hipStream_t stream) {
    const float* x          = (const float*)d_in[0];
    const int*   labels     = (const int*)d_in[1];
    const float* in_proj_w  = (const float*)d_in[2];
    const float* conv_w     = (const float*)d_in[3];
    const float* conv_b     = (const float*)d_in[4];
    const float* x_proj_w   = (const float*)d_in[5];
    const float* dt_w       = (const float*)d_in[6];
    const float* dt_b       = (const float*)d_in[7];
    const float* A_log      = (const float*)d_in[8];
    const float* D_param    = (const float*)d_in[9];
    const float* out_proj_w = (const float*)d_in[10];
    const float* norm_w     = (const float*)d_in[11];
    const float* normf_w    = (const float*)d_in[12];
    const float* cls_w      = (const float*)d_in[13];
    const float* cls_b      = (const float*)d_in[14];
    float* out = (float*)d_out;

    const size_t FULL_NEED = 234000000ull;   // ~233.5 MB full-path layout
    int scan_grid = (DI/256) * NBATCH * CHK;   // 768

    if (ws_size >= FULL_NEED) {
        // ---------------- FULL PATH (~233 MB) ----------------
        char* p = (char*)d_ws;
        bf16* h     = (bf16*)p;  p += (size_t)MTOK * DM * 2;
        bf16* xn    = (bf16*)p;  p += (size_t)MTOK * DM * 2;
        bf16* xz    = (bf16*)p;  p += (size_t)MTOK * 3072 * 2;       // xin|z, y over xin
        bf16* delta = (bf16*)p;  p += (size_t)MTOK * DI * 2;
        bf16* dbc   = (bf16*)p;  p += (size_t)MTOK * 128 * 2;        // padded to 128
        float* dbcf = (float*)p; p += (size_t)MTOK * 80 * 4;
        float* hst  = (float*)p; p += (size_t)NBATCH*DI*CHK*DS*4;
        float* Ssum = (float*)p; p += (size_t)NBATCH*DI*CHK*4;
        unsigned short* bound = (unsigned short*)p; p += (size_t)NBATCH*DI*CHK*4*2;
        float* rsb    = (float*)p; p += (size_t)MTOK * 4;
        float* pooled = (float*)p; p += NBATCH * DM * 4;
        short* inw_b = (short*)p;  p += (size_t)2*DI*DM * 2;
        short* xw_b  = (short*)p;  p += (size_t)80*DI * 2;
        short* ow_b  = (short*)p;  p += (size_t)DM*DI * 2;
        short* dtwp  = (short*)p;  p += (size_t)DI*128 * 2;

        cvt_kernel<<<(MTOK * DM) / 256, 256, 0, stream>>>(x, h, MTOK * DM);
        hipMemsetAsync(pooled, 0, NBATCH * DM * sizeof(float), stream);

        for (int l = 0; l < 4; l++) {
            const float* inw = in_proj_w + (size_t)l * 2 * DI * DM;
            const float* cwl = conv_w + (size_t)l * DI * 4;
            const float* cbl = conv_b + (size_t)l * DI;
            const float* xwl = x_proj_w + (size_t)l * (RNK + 2*DS) * DI;
            const float* dwl = dt_w + (size_t)l * DI * RNK;
            const float* dbl = dt_b + (size_t)l * DI;
            const float* All = A_log + (size_t)l * DI * DS;
            const float* Dpl = D_param + (size_t)l * DI;
            const float* owl = out_proj_w + (size_t)l * DM * DI;

            cvt_kernel<<<(2*DI*DM)/256, 256, 0, stream>>>(inw, (bf16*)inw_b, 2*DI*DM);
            cvt_kernel<<<(80*DI)/256, 256, 0, stream>>>(xwl, (bf16*)xw_b, 80*DI);
            cvt_kernel<<<(DM*DI)/256, 256, 0, stream>>>(owl, (bf16*)ow_b, DM*DI);
            cvt_pad_kernel<<<(DI*128)/256, 256, 0, stream>>>(dwl, (bf16*)dtwp, RNK, 128, DI*128);

            rmsnorm_kernel<<<MTOK, 256, 0, stream>>>(h, norm_w + (size_t)l * DM, xn, nullptr);

            // merged in_proj: xz[:,0:3072] = xn @ in_w^T  (xin | z)
            mgemm<0,0><<<dim3(3072/BN, MTOK/BM), 256, 0, stream>>>(
                (const short*)xn, DM, inw_b, DM, xz, 3072, MTOK, 3072, DM,
                nullptr, nullptr, nullptr, 0);

            hipMemsetAsync(dbcf, 0, (size_t)MTOK * 80 * sizeof(float), stream);

            // x_proj split-K (conv fused), A = xin half of xz (lda=3072)
            mgemm<4,1><<<dim3(1, MTOK/BM, KSPLIT), 256, 0, stream>>>(
                (const short*)xz, 3072, xw_b, DI, (bf16*)dbcf, 80, MTOK, 80, DI,
                cwl, cbl, nullptr, (DI/BK)/KSPLIT);
            cvt_pad_kernel<<<(MTOK*128)/256, 256, 0, stream>>>(dbcf, dbc, 80, 128, MTOK*128);

            // delta = softplus(dbc @ dtwp^T + dt_b)   (K=128 zero-padded)
            mgemm<1,0><<<dim3(DI/BN, MTOK/BM), 256, 0, stream>>>(
                (const short*)dbc, 128, dtwp, 128, delta, DI, MTOK, DI, 128,
                nullptr, nullptr, dbl, 0);

            scan_fused_kernel<1><<<scan_grid, 256, 0, stream>>>(
                xz, delta, dbc, All, Dpl, cwl, cbl, hst, Ssum, bound);
            scan_combine_kernel<<<(NBATCH*DI*DS)/256, 256, 0, stream>>>(hst, Ssum, All);
            scan_fused_kernel<2><<<scan_grid, 256, 0, stream>>>(
                xz, delta, dbc, All, Dpl, cwl, cbl, hst, Ssum, bound);

            // h += y @ out_w^T   (y in xz cols 0..1535, lda=3072)
            mgemm<2,0><<<dim3(DM/BN, MTOK/BM), 256, 0, stream>>>(
                (const short*)xz, 3072, ow_b, DI, h, DM, MTOK, DM, DI,
                nullptr, nullptr, nullptr, 0);
        }

        rmsnorm_kernel<<<MTOK, 256, 0, stream>>>(h, normf_w, nullptr, rsb);
        pool_kernel<<<dim3(NBATCH, DM/128, LSEQ/128), 128, 0, stream>>>(h, rsb, normf_w, pooled);
        head_kernel<<<1, 128, 0, stream>>>(pooled, cls_w, cls_b, labels, out);
        return;
    }

    // ---------------- FALLBACK PATH (R7, ~127 MB) ----------------
    char* p = (char*)d_ws;
    bf16* h   = (bf16*)p;                 p += (size_t)MTOK * DM * 2;
    bf16* xn  = (bf16*)p;                 p += (size_t)MTOK * DM * 2;
    bf16* xy  = (bf16*)p;                 p += (size_t)MTOK * DI * 2;
    bf16* dbc = (bf16*)p;                 p += (size_t)MTOK * 80 * 2;
    float* dbcf = (float*)p;              p += (size_t)MTOK * 80 * 4;
    float* hst = (float*)p;               p += (size_t)NBATCH*DI*CHK*DS*4;
    float* Ssum = (float*)p;              p += (size_t)NBATCH*DI*CHK*4;
    unsigned short* bound = (unsigned short*)p; p += (size_t)NBATCH*DI*CHK*4*2;
    float* rsb    = (float*)p;            p += (size_t)MTOK * 4;
    float* pooled = (float*)p;            p += NBATCH * DM * 4;
    short* inw_b = (short*)p;             p += (size_t)2*DI*DM * 2;
    short* xw_b  = (short*)p;             p += (size_t)80*DI * 2;
    short* ow_b  = (short*)p;             p += (size_t)DM*DI * 2;

    cvt_kernel<<<(MTOK * DM) / 256, 256, 0, stream>>>(x, h, MTOK * DM);
    hipMemsetAsync(pooled, 0, NBATCH * DM * sizeof(float), stream);

    for (int l = 0; l < 4; l++) {
        const float* inw = in_proj_w + (size_t)l * 2 * DI * DM;
        const float* cwl = conv_w + (size_t)l * DI * 4;
        const float* cbl = conv_b + (size_t)l * DI;
        const float* xwl = x_proj_w + (size_t)l * (RNK + 2*DS) * DI;
        const float* dwl = dt_w + (size_t)l * DI * RNK;
        const float* dbl = dt_b + (size_t)l * DI;
        const float* All = A_log + (size_t)l * DI * DS;
        const float* Dpl = D_param + (size_t)l * DI;
        const float* owl = out_proj_w + (size_t)l * DM * DI;

        cvt_kernel<<<(2*DI*DM)/256, 256, 0, stream>>>(inw, (bf16*)inw_b, 2*DI*DM);
        cvt_kernel<<<(80*DI)/256, 256, 0, stream>>>(xwl, (bf16*)xw_b, 80*DI);
        cvt_kernel<<<(DM*DI)/256, 256, 0, stream>>>(owl, (bf16*)ow_b, DM*DI);

        rmsnorm_kernel<<<MTOK, 256, 0, stream>>>(h, norm_w + (size_t)l * DM, xn, nullptr);

        mgemm<0,0><<<dim3(DI/BN, MTOK/BM), 256, 0, stream>>>(
            (const short*)xn, DM, inw_b, DM, xy, DI, MTOK, DI, DM,
            nullptr, nullptr, nullptr, 0);

        hipMemsetAsync(dbcf, 0, (size_t)MTOK * 80 * sizeof(float), stream);
        mgemm<4,1><<<dim3(1, MTOK/BM, KSPLIT), 256, 0, stream>>>(
            (const short*)xy, DI, xw_b, DI, (bf16*)dbcf, 80, MTOK, 80, DI,
            cwl, cbl, nullptr, (DI/BK)/KSPLIT);
        cvt_kernel<<<(MTOK*80)/256, 256, 0, stream>>>(dbcf, dbc, MTOK*80);

        scan_pass_kernel<1><<<scan_grid, 256, 0, stream>>>(
            xy, dbc, All, Dpl, dwl, dbl, cwl, cbl, hst, Ssum, bound);
        scan_combine_kernel<<<(NBATCH*DI*DS)/256, 256, 0, stream>>>(hst, Ssum, All);
        scan_pass_kernel<2><<<scan_grid, 256, 0, stream>>>(
            xy, dbc, All, Dpl, dwl, dbl, cwl, cbl, hst, Ssum, bound);

        mgemm<3,0><<<dim3(DI/BN, MTOK/BM), 256, 0, stream>>>(
            (const short*)xn, DM, inw_b + (size_t)DI*DM, DM, xy, DI, MTOK, DI, DM,
            nullptr, nullptr, nullptr, 0);

        mgemm<2,0><<<dim3(DM/BN, MTOK/BM), 256, 0, stream>>>(
            (const short*)xy, DI, ow_b, DI, h, DM, MTOK, DM, DI,
            nullptr, nullptr, nullptr, 0);
    }

    rmsnorm_kernel<<<MTOK, 256, 0, stream>>>(h, normf_w, nullptr, rsb);
    pool_kernel<<<dim3(NBATCH, DM/128, LSEQ/128), 128, 0, stream>>>(h, rsb, normf_w, pooled);
    head_kernel<<<1, 128, 0, stream>>>(pooled, cls_w, cls_b, labels, out);
}

// Round 9
// 1420.631 us; speedup vs baseline: 1.7500x; 1.7500x over previous
//
#include <hip/hip_runtime.h>
#include <hip/hip_bf16.h>
#include <math.h>

#define MTOK 16384      // B*L tokens
#define DM   768
#define DI   1536
#define DS   16
#define RNK  48
#define LSEQ 2048
#define NBATCH 8
#define EPSV 1e-5f
#define CHK  64         // time chunks for the scan (64 -> grid 3072, 12 blk/CU)
#define CLEN (LSEQ / CHK)
#define BM 128
#define BN 128
#define BK 32
#define KSPLIT 8        // split-K factor for the x_proj GEMM
#define EPS_STRIDE 72   // epilogue LDS row stride (shorts)

typedef __hip_bfloat16 bf16;
typedef __attribute__((ext_vector_type(8))) short short8;
typedef __attribute__((ext_vector_type(4))) float floatx4;

__device__ __forceinline__ float b2f(bf16 v){ return __bfloat162float(v); }
__device__ __forceinline__ bf16  f2b(float v){ return __float2bfloat16(v); }
__device__ __forceinline__ float u2f(unsigned short u){
    union { unsigned int i; float f; } v; v.i = ((unsigned int)u) << 16; return v.f;
}
__device__ __forceinline__ float silu_f(float x){
    return x * __builtin_amdgcn_rcpf(1.f + __expf(-x));
}
__device__ __forceinline__ void gload_lds16(const void* g, void* l) {
    __builtin_amdgcn_global_load_lds(
        (const __attribute__((address_space(1))) void*)g,
        (__attribute__((address_space(3))) void*)l, 16, 0, 0);
}

// ---------------- fp32 -> bf16 convert ----------------
__global__ __launch_bounds__(256) void cvt_kernel(
    const float* __restrict__ x, bf16* __restrict__ h, int n)
{
    int i = blockIdx.x * 256 + threadIdx.x;
    if (i < n) h[i] = f2b(x[i]);
}

// ---------------- RMSNorm over 768 (3 elems/thread) ----------------
__global__ __launch_bounds__(256) void rmsnorm_kernel(
    const bf16* __restrict__ in, const float* __restrict__ w,
    bf16* __restrict__ out, float* __restrict__ rs_out)
{
    int row = blockIdx.x;
    const bf16* r = in + (size_t)row * DM;
    float v0 = b2f(r[threadIdx.x]);
    float v1 = b2f(r[threadIdx.x + 256]);
    float v2 = b2f(r[threadIdx.x + 512]);
    float s = v0*v0 + v1*v1 + v2*v2;
    for (int o = 32; o > 0; o >>= 1) s += __shfl_down(s, o, 64);
    __shared__ float red[4];
    if ((threadIdx.x & 63) == 0) red[threadIdx.x >> 6] = s;
    __syncthreads();
    float rs = rsqrtf((red[0]+red[1]+red[2]+red[3]) * (1.f/DM) + EPSV);
    if (rs_out && threadIdx.x == 0) rs_out[row] = rs;
    if (out) {
        out[(size_t)row*DM + threadIdx.x]       = f2b(v0 * rs * w[threadIdx.x]);
        out[(size_t)row*DM + threadIdx.x + 256] = f2b(v1 * rs * w[threadIdx.x + 256]);
        out[(size_t)row*DM + threadIdx.x + 512] = f2b(v2 * rs * w[threadIdx.x + 512]);
    }
}

// ---------------- bf16 MFMA GEMM: C[M,N] (op)= A[M,K] @ W[N,K]^T ----------------
// 128x128 tile, BK=32, 4 waves 2x2, each wave 4x4 mfma_f32_16x16x32_bf16.
// XOR-swizzled LDS tiles, wide-store epilogue via per-wave LDS bounce.
// MODE 0: C = acc ; MODE 2: C += acc ; MODE 3: C = C * silu(acc)
// MODE 4: atomicAdd fp32 partial into (float*)C  (split-K path, blockIdx.z)
// CONVA=1: A-tile = silu(causal dwconv4(A)) computed on the fly (x_proj path)
template<int MODE, int CONVA>
__global__ __launch_bounds__(256) void mgemm(
    const short* __restrict__ A, int lda,
    const short* __restrict__ W, int ldw,
    bf16* __restrict__ C, int ldc,
    int M, int N, int K,
    const float* __restrict__ cw, const float* __restrict__ cb,
    int ksteps_per_split)
{
    __shared__ __attribute__((aligned(16))) short As[BM*BK];
    __shared__ __attribute__((aligned(16))) short Bs[BN*BK];
    const int bm = blockIdx.y * BM;
    const int bn = blockIdx.x * BN;
    const int tid = threadIdx.x;
    const int wave = tid >> 6;
    const int lane = tid & 63;
    const int wm = (wave & 1) * 64;
    const int wn = (wave >> 1) * 64;
    const int r15 = lane & 15;
    const int quad = lane >> 4;

    int kbeg = 0, kend = K;
    if (MODE == 4) {
        kbeg = blockIdx.z * ksteps_per_split * BK;
        kend = kbeg + ksteps_per_split * BK;
        if (kend > K) kend = K;
    }

    const int srow = wave*32 + (lane >> 2);
    const int swz = (lane & 3) ^ ((lane >> 2) & 3);
    int wr0 = bn + srow;      if (wr0 >= N) wr0 = N - 1;
    int wr1 = bn + srow + 16; if (wr1 >= N) wr1 = N - 1;

    floatx4 acc[4][4];
    const floatx4 zero = {0.f, 0.f, 0.f, 0.f};
    #pragma unroll
    for (int i = 0; i < 4; i++)
        #pragma unroll
        for (int j = 0; j < 4; j++) acc[i][j] = zero;

    const int kk = tid & 31;
    const int tg = tid >> 5;
    const int sA = CONVA ? quad : (quad ^ (r15 & 3));
    const int sB = quad ^ (r15 & 3);

    for (int k0 = kbeg; k0 < kend; k0 += BK) {
        if (CONVA) {
            int e = k0 + kk;
            float c0 = cw[e*4+0], c1 = cw[e*4+1], c2 = cw[e*4+2], c3 = cw[e*4+3];
            float cbe = cb[e];
            int g0 = bm + tg*16;
            const unsigned short* xp = (const unsigned short*)A + (size_t)g0 * lda + e;
            float p0 = 0.f, p1 = 0.f, p2 = 0.f;
            if ((g0 & (LSEQ-1)) != 0) {
                p0 = u2f(xp[-(ptrdiff_t)3*lda]);
                p1 = u2f(xp[-(ptrdiff_t)2*lda]);
                p2 = u2f(xp[-(ptrdiff_t)1*lda]);
            }
            #pragma unroll
            for (int i = 0; i < 16; i++) {
                float xt = u2f(xp[(size_t)i * lda]);
                float xv = silu_f(cbe + c0*p0 + c1*p1 + c2*p2 + c3*xt);
                p0 = p1; p1 = p2; p2 = xt;
                bf16 t = f2b(xv);
                As[(tg*16 + i)*BK + kk] = *(short*)&t;
            }
        } else {
            gload_lds16(A + (size_t)(bm + srow)      * lda + k0 + swz*8, &As[(wave*32)*BK]);
            gload_lds16(A + (size_t)(bm + srow + 16) * lda + k0 + swz*8, &As[(wave*32 + 16)*BK]);
        }
        gload_lds16(W + (size_t)wr0 * ldw + k0 + swz*8, &Bs[(wave*32)*BK]);
        gload_lds16(W + (size_t)wr1 * ldw + k0 + swz*8, &Bs[(wave*32 + 16)*BK]);
        __syncthreads();

        short8 af[4], bfr[4];
        #pragma unroll
        for (int i = 0; i < 4; i++) af[i]  = *(const short8*)&As[(wm + i*16 + r15)*BK + sA*8];
        #pragma unroll
        for (int i = 0; i < 4; i++) bfr[i] = *(const short8*)&Bs[(wn + i*16 + r15)*BK + sB*8];
        #pragma unroll
        for (int mt = 0; mt < 4; mt++)
            #pragma unroll
            for (int nt = 0; nt < 4; nt++)
                acc[mt][nt] = __builtin_amdgcn_mfma_f32_16x16x32_bf16(
                    af[mt], bfr[nt], acc[mt][nt], 0, 0, 0);
        __syncthreads();
    }

    if (MODE == 4) {
        float* Cf = (float*)C;
        #pragma unroll
        for (int nt = 0; nt < 4; nt++) {
            int n = bn + wn + nt*16 + r15;
            if (n >= N) continue;
            #pragma unroll
            for (int mt = 0; mt < 4; mt++)
                #pragma unroll
                for (int reg = 0; reg < 4; reg++) {
                    int m = bm + wm + mt*16 + quad*4 + reg;
                    atomicAdd(&Cf[(size_t)m * ldc + n], acc[mt][nt][reg]);
                }
        }
        return;
    }

    // ---- wide-store epilogue: bounce each wave's 64x64 tile through LDS ----
    short* ep = ((wave & 2) ? Bs : As) + (wave & 1) * 1152;
    const int lr = lane >> 2;
    const int lc = lane & 3;
    #pragma unroll
    for (int mt = 0; mt < 4; mt++) {
        #pragma unroll
        for (int nt = 0; nt < 4; nt++)
            #pragma unroll
            for (int reg = 0; reg < 4; reg++) {
                bf16 t = f2b(acc[mt][nt][reg]);
                ep[(quad*4 + reg)*EPS_STRIDE + nt*16 + r15] = *(short*)&t;
            }
        short8 v0 = *(const short8*)&ep[lr*EPS_STRIDE + lc*16];
        short8 v1 = *(const short8*)&ep[lr*EPS_STRIDE + lc*16 + 8];
        int gm = bm + wm + mt*16 + lr;
        int gn = bn + wn + lc*16;
        if (gn < N) {
            bf16* cp = C + (size_t)gm * ldc + gn;
            if (MODE == 0) {
                *(short8*)cp       = v0;
                *(short8*)(cp + 8) = v1;
            } else {
                short8 c0 = *(const short8*)cp;
                short8 c1 = *(const short8*)(cp + 8);
                short8 o0, o1;
                #pragma unroll
                for (int j = 0; j < 8; j++) {
                    float cv0 = u2f((unsigned short)c0[j]);
                    float av0 = u2f((unsigned short)v0[j]);
                    float cv1 = u2f((unsigned short)c1[j]);
                    float av1 = u2f((unsigned short)v1[j]);
                    float r0 = (MODE == 2) ? (cv0 + av0) : (cv0 * silu_f(av0));
                    float r1 = (MODE == 2) ? (cv1 + av1) : (cv1 * silu_f(av1));
                    bf16 t0 = f2b(r0), t1 = f2b(r1);
                    o0[j] = *(short*)&t0;
                    o1[j] = *(short*)&t1;
                }
                *(short8*)cp       = o0;
                *(short8*)(cp + 8) = o1;
            }
        }
    }
}

// ---------------- chunked selective scan (R7 structure, CHK=64) ----------------
template<int PASS>
__global__ __launch_bounds__(256) void scan_pass_kernel(
    bf16* __restrict__ xy, const bf16* __restrict__ dbc,
    const float* __restrict__ A_log, const float* __restrict__ Dp,
    const float* __restrict__ dtw, const float* __restrict__ dtb,
    const float* __restrict__ cw, const float* __restrict__ cb,
    float* __restrict__ hst, float* __restrict__ Ssum,
    unsigned short* __restrict__ bound)
{
    int e = (blockIdx.x % (DI/256)) * 256 + threadIdx.x;
    int b = (blockIdx.x / (DI/256)) & (NBATCH - 1);
    int c = blockIdx.x / ((DI/256) * NBATCH);
    int t0 = c * CLEN;

    float w[RNK];
    #pragma unroll
    for (int r = 0; r < RNK; r++) w[r] = dtw[e*RNK + r];
    float a[DS];
    #pragma unroll
    for (int n = 0; n < DS; n++) a[n] = -__expf(A_log[e*DS + n]);
    float c0 = cw[e*4+0], c1 = cw[e*4+1], c2 = cw[e*4+2], c3 = cw[e*4+3];
    float cbe = cb[e], dtbe = dtb[e], dpe = Dp[e];

    size_t sidx = ((size_t)(b*DI) + e) * CHK + c;
    float hh[DS];
    if (PASS == 1) {
        #pragma unroll
        for (int n = 0; n < DS; n++) hh[n] = 0.f;
    } else {
        #pragma unroll
        for (int n = 0; n < DS; n++) hh[n] = hst[sidx*DS + n];
    }

    unsigned short* xrow = (unsigned short*)(xy + ((size_t)(b*LSEQ) + t0) * DI + e);
    const unsigned short* drow = (const unsigned short*)(dbc + ((size_t)(b*LSEQ) + t0) * 80);

    unsigned short r0, r1, r2;
    if (PASS == 1) {
        if (c == 0) { r0 = 0; r1 = 0; r2 = 0; }
        else {
            r0 = xrow[-(ptrdiff_t)3*DI];
            r1 = xrow[-(ptrdiff_t)2*DI];
            r2 = xrow[-(ptrdiff_t)1*DI];
        }
        bound[sidx*4+0] = r0; bound[sidx*4+1] = r1; bound[sidx*4+2] = r2;
    } else {
        r0 = bound[sidx*4+0]; r1 = bound[sidx*4+1]; r2 = bound[sidx*4+2];
    }
    float p0 = u2f(r0), p1 = u2f(r1), p2 = u2f(r2);

    float S = 0.f;
    for (int t = 0; t < CLEN; t++) {
        float xt = u2f(xrow[(size_t)t * DI]);
        float xv = silu_f(cbe + c0*p0 + c1*p1 + c2*p2 + c3*xt);
        p0 = p1; p1 = p2; p2 = xt;

        uint4 q[5];
        const uint4* d4 = (const uint4*)(drow + (size_t)t * 80);
        #pragma unroll
        for (int i = 0; i < 5; i++) q[i] = d4[i];
        uint4 q2[5];
        #pragma unroll
        for (int i = 0; i < 5; i++) q2[i] = d4[5 + i];
        const unsigned short* ds = (const unsigned short*)q;
        const unsigned short* ds2 = (const unsigned short*)q2;

        float acc = dtbe;
        #pragma unroll
        for (int r = 0; r < RNK; r++) acc += w[r] * u2f(ds[r]);
        float d = (acc > 20.f) ? acc : __logf(1.f + __expf(acc));
        float dx = d * xv;
        #pragma unroll
        for (int n = 0; n < DS; n++)
            hh[n] = __expf(d * a[n]) * hh[n] + dx * u2f(ds[RNK + n]);

        if (PASS == 1) {
            S += d;
        } else {
            float y = xv * dpe;
            #pragma unroll
            for (int n = 0; n < DS; n++) y += hh[n] * u2f(ds2[n]);
            bf16 yb = f2b(y);
            xrow[(size_t)t * DI] = *(unsigned short*)&yb;
        }
    }
    if (PASS == 1) {
        #pragma unroll
        for (int n = 0; n < DS; n++) hst[sidx*DS + n] = hh[n];
        Ssum[sidx] = S;
    }
}

// ---------------- combine chunk states ----------------
__global__ __launch_bounds__(256) void scan_combine_kernel(
    float* __restrict__ hst, const float* __restrict__ Ssum,
    const float* __restrict__ A_log)
{
    int tid = blockIdx.x * 256 + threadIdx.x;
    int n = tid & 15;
    int bee = tid >> 4;
    int e = bee % DI;
    float a = -__expf(A_log[e*DS + n]);
    float run = 0.f;
    for (int c = 0; c < CHK; c++) {
        size_t idx = ((size_t)bee * CHK + c) * DS + n;
        float tmp = hst[idx];
        hst[idx] = run;
        run = tmp + __expf(a * Ssum[(size_t)bee*CHK + c]) * run;
    }
}

// ---------------- pooled / head ----------------
__global__ __launch_bounds__(128) void pool_kernel(
    const bf16* __restrict__ h, const float* __restrict__ rs,
    const float* __restrict__ wf, float* __restrict__ pooled)
{
    int b = blockIdx.x, dc = blockIdx.y, tc = blockIdx.z;
    int d = dc * 128 + threadIdx.x;
    float s = 0.f;
    int t0 = tc * 128;
    for (int t = t0; t < t0 + 128; t++) {
        int row = b * LSEQ + t;
        s += b2f(h[(size_t)row * DM + d]) * rs[row];
    }
    atomicAdd(&pooled[b * DM + d], s * wf[d] * (1.f / LSEQ));
}

__global__ __launch_bounds__(128) void head_kernel(
    const float* __restrict__ pooled, const float* __restrict__ cls_w,
    const float* __restrict__ cls_b, const int* __restrict__ labels,
    float* __restrict__ out)
{
    __shared__ float lg[80];
    int tid = threadIdx.x;
    if (tid < 80) {
        int b = tid / 10, c = tid % 10;
        float s = cls_b[c];
        for (int d = 0; d < DM; d++) s += pooled[b * DM + d] * cls_w[c * DM + d];
        lg[tid] = s;
    }
    __syncthreads();
    if (tid == 0) {
        float loss = 0.f;
        for (int b = 0; b < NBATCH; b++) {
            float mx = -1e30f;
            for (int c = 0; c < 10; c++) mx = fmaxf(mx, lg[b*10+c]);
            float se = 0.f;
            for (int c = 0; c < 10; c++) se += expf(lg[b*10+c] - mx);
            float lse = mx + logf(se);
            loss -= (lg[b*10 + labels[b]] - lse);
            for (int c = 0; c < 10; c++) out[b*10+c] = lg[b*10+c];
        }
        out[80] = loss / NBATCH;
    }
}

extern "C" void kernel_launch(void* const* d_in, const int* in_sizes, int n_in,
                              void* d_out, int out_size, void* d_ws, size_t ws_size,
                              hipStream_t stream) {
    const float* x          = (const float*)d_in[0];
    const int*   labels     = (const int*)d_in[1];
    const float* in_proj_w  = (const float*)d_in[2];
    const float* conv_w     = (const float*)d_in[3];
    const float* conv_b     = (const float*)d_in[4];
    const float* x_proj_w   = (const float*)d_in[5];
    const float* dt_w       = (const float*)d_in[6];
    const float* dt_b       = (const float*)d_in[7];
    const float* A_log      = (const float*)d_in[8];
    const float* D_param    = (const float*)d_in[9];
    const float* out_proj_w = (const float*)d_in[10];
    const float* norm_w     = (const float*)d_in[11];
    const float* normf_w    = (const float*)d_in[12];
    const float* cls_w      = (const float*)d_in[13];
    const float* cls_b      = (const float*)d_in[14];
    float* out = (float*)d_out;

    // workspace layout (~176 MB; ws_size >= 234 MB proven in R8)
    char* p = (char*)d_ws;
    bf16* h   = (bf16*)p;                 p += (size_t)MTOK * DM * 2;
    bf16* xn  = (bf16*)p;                 p += (size_t)MTOK * DM * 2;
    bf16* xy  = (bf16*)p;                 p += (size_t)MTOK * DI * 2;
    bf16* dbc = (bf16*)p;                 p += (size_t)MTOK * 80 * 2;
    float* dbcf = (float*)p;              p += (size_t)MTOK * 80 * 4;
    float* hst = (float*)p;               p += (size_t)NBATCH*DI*CHK*DS*4;   // 50.3 MB
    float* Ssum = (float*)p;              p += (size_t)NBATCH*DI*CHK*4;      // 3.1 MB
    unsigned short* bound = (unsigned short*)p; p += (size_t)NBATCH*DI*CHK*4*2; // 6.3 MB
    float* rsb    = (float*)p;            p += (size_t)MTOK * 4;
    float* pooled = (float*)p;            p += NBATCH * DM * 4;
    short* inw_b = (short*)p;             p += (size_t)2*DI*DM * 2;
    short* xw_b  = (short*)p;             p += (size_t)80*DI * 2;
    short* ow_b  = (short*)p;             p += (size_t)DM*DI * 2;

    cvt_kernel<<<(MTOK * DM) / 256, 256, 0, stream>>>(x, h, MTOK * DM);
    hipMemsetAsync(pooled, 0, NBATCH * DM * sizeof(float), stream);

    int scan_grid = (DI/256) * NBATCH * CHK;   // 3072

    for (int l = 0; l < 4; l++) {
        const float* inw = in_proj_w + (size_t)l * 2 * DI * DM;
        const float* cwl = conv_w + (size_t)l * DI * 4;
        const float* cbl = conv_b + (size_t)l * DI;
        const float* xwl = x_proj_w + (size_t)l * (RNK + 2*DS) * DI;
        const float* dwl = dt_w + (size_t)l * DI * RNK;
        const float* dbl = dt_b + (size_t)l * DI;
        const float* All = A_log + (size_t)l * DI * DS;
        const float* Dpl = D_param + (size_t)l * DI;
        const float* owl = out_proj_w + (size_t)l * DM * DI;

        cvt_kernel<<<(2*DI*DM)/256, 256, 0, stream>>>(inw, (bf16*)inw_b, 2*DI*DM);
        cvt_kernel<<<(80*DI)/256, 256, 0, stream>>>(xwl, (bf16*)xw_b, 80*DI);
        cvt_kernel<<<(DM*DI)/256, 256, 0, stream>>>(owl, (bf16*)ow_b, DM*DI);

        rmsnorm_kernel<<<MTOK, 256, 0, stream>>>(h, norm_w + (size_t)l * DM, xn, nullptr);

        // xin = xn @ in_w[0:1536]^T   (MFMA)
        mgemm<0,0><<<dim3(DI/BN, MTOK/BM), 256, 0, stream>>>(
            (const short*)xn, DM, inw_b, DM, xy, DI, MTOK, DI, DM,
            nullptr, nullptr, 0);

        // x_proj split-K (conv fused into A staging)
        hipMemsetAsync(dbcf, 0, (size_t)MTOK * 80 * sizeof(float), stream);
        mgemm<4,1><<<dim3(1, MTOK/BM, KSPLIT), 256, 0, stream>>>(
            (const short*)xy, DI, xw_b, DI, (bf16*)dbcf, 80, MTOK, 80, DI,
            cwl, cbl, (DI/BK)/KSPLIT);
        cvt_kernel<<<(MTOK*80)/256, 256, 0, stream>>>(dbcf, dbc, MTOK*80);

        // chunked scan: pass1 -> combine -> pass2 (y overwrites xin in xy)
        scan_pass_kernel<1><<<scan_grid, 256, 0, stream>>>(
            xy, dbc, All, Dpl, dwl, dbl, cwl, cbl, hst, Ssum, bound);
        scan_combine_kernel<<<(NBATCH*DI*DS)/256, 256, 0, stream>>>(hst, Ssum, All);
        scan_pass_kernel<2><<<scan_grid, 256, 0, stream>>>(
            xy, dbc, All, Dpl, dwl, dbl, cwl, cbl, hst, Ssum, bound);

        // gating: y *= silu(xn @ in_w[1536:3072]^T)   (MFMA)
        mgemm<3,0><<<dim3(DI/BN, MTOK/BM), 256, 0, stream>>>(
            (const short*)xn, DM, inw_b + (size_t)DI*DM, DM, xy, DI, MTOK, DI, DM,
            nullptr, nullptr, 0);

        // h += y @ out_w^T   (MFMA)
        mgemm<2,0><<<dim3(DM/BN, MTOK/BM), 256, 0, stream>>>(
            (const short*)xy, DI, ow_b, DI, h, DM, MTOK, DM, DI,
            nullptr, nullptr, 0);
    }

    rmsnorm_kernel<<<MTOK, 256, 0, stream>>>(h, normf_w, nullptr, rsb);
    pool_kernel<<<dim3(NBATCH, DM/128, LSEQ/128), 128, 0, stream>>>(h, rsb, normf_w, pooled);
    head_kernel<<<1, 128, 0, stream>>>(pooled, cls_w, cls_b, labels, out);
}